// Round 1
// 521.540 us; speedup vs baseline: 1.5635x; 1.5635x over previous
//
#include <hip/hip_runtime.h>
#include <math.h>
#include <stdint.h>

// BS=8, ROI=512, D=1024, G=16, DH=64, GEO=64, N_total=4096
// All I/O float32.

using f16   = _Float16;
using f16x4 = __attribute__((ext_vector_type(4))) f16;
using f16x8 = __attribute__((ext_vector_type(8))) f16;
using f32x4 = __attribute__((ext_vector_type(4))) float;

__device__ __forceinline__ float fast_tanh(float x) {
    const float ax = fabsf(x);
    const float e = __expf(-2.0f * ax);
    const float t = (1.0f - e) / (1.0f + e);
    return copysignf(t, x);
}

// async 16B/lane global->LDS copy; lds dest must be wave-uniform, HW adds lane*16
__device__ __forceinline__ void cp16(void* lds, const void* g) {
    __builtin_amdgcn_global_load_lds(
        (const __attribute__((address_space(1))) uint32_t*)g,
        (__attribute__((address_space(3))) uint32_t*)lds, 16, 0, 0);
}

// ---------------------------------------------------------------- geometry
__global__ __launch_bounds__(256) void geom_kernel(
    const float* __restrict__ boxes,
    float* __restrict__ gcx, float* __restrict__ gcy,
    float* __restrict__ gw,  float* __restrict__ glw, float* __restrict__ glh)
{
    const int i = blockIdx.x * 256 + threadIdx.x;
    if (i >= 4096) return;
    const float x1 = boxes[i * 4 + 0];
    const float y1 = boxes[i * 4 + 1];
    const float x2 = boxes[i * 4 + 2];
    const float y2 = boxes[i * 4 + 3];
    const float w = x2 - x1, h = y2 - y1;
    gcx[i] = 0.5f * (x1 + x2);
    gcy[i] = 0.5f * (y1 + y2);
    gw[i]  = w;
    glw[i] = logf(w);
    glh[i] = logf(h);
}

// ------------------------------------------------- fp32 -> split f16 hi/lo pack
// src: [nrows=grid.x, 1024] f32 row-major.
// dst: [nrows, 2048] f16. Per 32-k chunk s: cols [64s,64s+64) hold {hi[0..32) | lo[0..32)},
// pre-swizzled: in-chunk index ic stored at (ic ^ ((row&7)<<3)) so that a LINEAR
// global_load_lds into a [rows][64] f16 LDS tile yields bank-conflict-free
// ds_read_b128 fragment reads (T2 swizzle, both-sides-consistent).
__global__ __launch_bounds__(256) void split_f16_kernel(
    const float* __restrict__ src, f16* __restrict__ dst)
{
    const int m = blockIdx.x;
    const int k = threadIdx.x << 2;                 // 4 consecutive k per thread
    const float4 v = *reinterpret_cast<const float4*>(src + (size_t)m * 1024 + k);
    f16x4 hi, lo;
    hi[0] = (f16)v.x; hi[1] = (f16)v.y; hi[2] = (f16)v.z; hi[3] = (f16)v.w;
    lo[0] = (f16)(v.x - (float)hi[0]);
    lo[1] = (f16)(v.y - (float)hi[1]);
    lo[2] = (f16)(v.z - (float)hi[2]);
    lo[3] = (f16)(v.w - (float)hi[3]);
    const int s  = k >> 5;
    const int ic = k & 31;
    const int sw = (m & 7) << 3;                    // XOR on f16-index bits 3..5
    f16* base = dst + (size_t)m * 2048 + (s << 6);
    *reinterpret_cast<f16x4*>(base + (ic ^ sw))        = hi;
    *reinterpret_cast<f16x4*>(base + ((ic + 32) ^ sw)) = lo;
}

// ---------------------------------------- Q & K projections, split-f16 MFMA
// C[m,n] = sum_k A[m,k]*B[n,k] + bias[n], M=4096, N=1024, K=1024.
// z=0 -> Q, z=1 -> K. 128x128 tile, 4 waves 2x2, 64x64 per wave (4x4 16x16 frags).
// 3-term split: hi*hi + lo*hi + hi*lo accumulated in fp32.
__global__ __launch_bounds__(256) void gemm_qk_f16(
    const f16* __restrict__ xs, const f16* __restrict__ wqs, const f16* __restrict__ wks,
    const float* __restrict__ b_q, const float* __restrict__ b_k,
    float* __restrict__ qout, float* __restrict__ kout)
{
    const bool isK = (blockIdx.z != 0);
    const f16* Bmat   = isK ? wks : wqs;
    const float* bias = isK ? b_k : b_q;
    float* C          = isK ? kout : qout;
    const int m0 = blockIdx.y << 7;
    const int n0 = blockIdx.x << 7;

    __shared__ f16 As[8192];   // [128 rows][64 f16] = 16KB, swizzled content
    __shared__ f16 Bs[8192];

    const int tid  = threadIdx.x;
    const int lane = tid & 63;
    const int w    = tid >> 6;
    const int wr   = (w >> 1) << 6;   // wave row base (0/64)
    const int wc   = (w & 1) << 6;    // wave col base (0/64)
    const int srow = lane >> 3;       // staging: row within 8-row chunk
    const int sseg = (lane & 7) << 4; // staging: byte segment within 128B row
    const int l15  = lane & 15;
    const int kgrp = (lane >> 4) << 3; // fragment k-offset: 0,8,16,24

    f32x4 acc[4][4] = {};

    // precomputed swizzled fragment offsets (f16 units); lo plane = hi ^ 32
    int aoff[4], boff[4];
    #pragma unroll
    for (int f = 0; f < 4; ++f) {
        const int ra = wr + (f << 4) + l15;
        aoff[f] = (ra << 6) + (kgrp ^ ((ra & 7) << 3));
        const int rb = wc + (f << 4) + l15;
        boff[f] = (rb << 6) + (kgrp ^ ((rb & 7) << 3));
    }

    for (int s = 0; s < 32; ++s) {
        const size_t gb = (size_t)(s << 7) + sseg;   // byte offset within packed row
        #pragma unroll
        for (int it = 0; it < 4; ++it) {
            const int ch = (w << 2) + it;            // 1KB chunk 0..15
            const int gr = (ch << 3) + srow;         // tile row 0..127
            cp16((char*)As + (ch << 10), (const char*)xs   + (size_t)(m0 + gr) * 4096 + gb);
            cp16((char*)Bs + (ch << 10), (const char*)Bmat + (size_t)(n0 + gr) * 4096 + gb);
        }
        __syncthreads();

        f16x8 ah[4], al[4], bh[4], bl[4];
        #pragma unroll
        for (int f = 0; f < 4; ++f) {
            ah[f] = *reinterpret_cast<const f16x8*>(As + aoff[f]);
            al[f] = *reinterpret_cast<const f16x8*>(As + (aoff[f] ^ 32));
            bh[f] = *reinterpret_cast<const f16x8*>(Bs + boff[f]);
            bl[f] = *reinterpret_cast<const f16x8*>(Bs + (boff[f] ^ 32));
        }
        #pragma unroll
        for (int i = 0; i < 4; ++i)
            #pragma unroll
            for (int j = 0; j < 4; ++j) {
                acc[i][j] = __builtin_amdgcn_mfma_f32_16x16x32_f16(ah[i], bh[j], acc[i][j], 0, 0, 0);
                acc[i][j] = __builtin_amdgcn_mfma_f32_16x16x32_f16(al[i], bh[j], acc[i][j], 0, 0, 0);
                acc[i][j] = __builtin_amdgcn_mfma_f32_16x16x32_f16(ah[i], bl[j], acc[i][j], 0, 0, 0);
            }
        __syncthreads();
    }

    const int rgrp = (lane >> 4) << 2;
    #pragma unroll
    for (int j = 0; j < 4; ++j) {
        const int col = n0 + wc + (j << 4) + l15;    // D col = lane&15
        const float bv = bias[col];
        #pragma unroll
        for (int i = 0; i < 4; ++i) {
            const int row = m0 + wr + (i << 4) + rgrp; // D row = (lane>>4)*4 + reg
            #pragma unroll
            for (int r = 0; r < 4; ++r)
                C[(size_t)(row + r) * 1024 + col] = acc[i][j][r] + bv;
        }
    }
}

// -------------------- y_t[b,g,o,j] = sum_d x[b,j,d]*W_gc[g,o,d], split-f16 MFMA
// Per z=b*16+g: M=512 (j), N=64 (o), K=1024. Tile 128(j)x64(o), waves 2x2:
// wave tile 64(j)x32(o) = 4x2 frags. Operands SWAPPED in mfma so o lands on the
// reg-dim and j on lane&15 -> coalesced 64B stores into the transposed layout.
__global__ __launch_bounds__(256) void gemm_yt_f16(
    const f16* __restrict__ xs, const f16* __restrict__ wgs,
    float* __restrict__ y_t)
{
    const int z = blockIdx.z;            // b*16+g
    const int b = z >> 4, g = z & 15;
    const int m0 = blockIdx.y << 7;      // j tile base
    const f16* A    = xs  + (size_t)(b << 9) * 2048;   // rows j of batch b
    const f16* Bmat = wgs + (size_t)(g << 6) * 2048;   // rows o of group g
    float* C = y_t + (size_t)z * 64 * 512;

    __shared__ f16 As[8192];   // [128][64]
    __shared__ f16 Bs[4096];   // [64][64]

    const int tid  = threadIdx.x;
    const int lane = tid & 63;
    const int w    = tid >> 6;
    const int wr   = (w >> 1) << 6;   // j base 0/64
    const int wc   = (w & 1) << 5;    // o base 0/32
    const int srow = lane >> 3;
    const int sseg = (lane & 7) << 4;
    const int l15  = lane & 15;
    const int kgrp = (lane >> 4) << 3;

    f32x4 acc[4][2] = {};

    int aoff[4], boff[2];
    #pragma unroll
    for (int f = 0; f < 4; ++f) {
        const int ra = wr + (f << 4) + l15;
        aoff[f] = (ra << 6) + (kgrp ^ ((ra & 7) << 3));
    }
    #pragma unroll
    for (int f = 0; f < 2; ++f) {
        const int rb = wc + (f << 4) + l15;
        boff[f] = (rb << 6) + (kgrp ^ ((rb & 7) << 3));
    }

    for (int s = 0; s < 32; ++s) {
        const size_t gb = (size_t)(s << 7) + sseg;
        #pragma unroll
        for (int it = 0; it < 4; ++it) {
            const int ch = (w << 2) + it;            // 0..15
            cp16((char*)As + (ch << 10),
                 (const char*)A + (size_t)(m0 + (ch << 3) + srow) * 4096 + gb);
        }
        #pragma unroll
        for (int it = 0; it < 2; ++it) {
            const int ch = (w << 1) + it;            // 0..7
            cp16((char*)Bs + (ch << 10),
                 (const char*)Bmat + (size_t)((ch << 3) + srow) * 4096 + gb);
        }
        __syncthreads();

        f16x8 ah[4], al[4], bh[2], bl[2];
        #pragma unroll
        for (int f = 0; f < 4; ++f) {
            ah[f] = *reinterpret_cast<const f16x8*>(As + aoff[f]);
            al[f] = *reinterpret_cast<const f16x8*>(As + (aoff[f] ^ 32));
        }
        #pragma unroll
        for (int f = 0; f < 2; ++f) {
            bh[f] = *reinterpret_cast<const f16x8*>(Bs + boff[f]);
            bl[f] = *reinterpret_cast<const f16x8*>(Bs + (boff[f] ^ 32));
        }
        #pragma unroll
        for (int i = 0; i < 4; ++i)
            #pragma unroll
            for (int j = 0; j < 2; ++j) {
                acc[i][j] = __builtin_amdgcn_mfma_f32_16x16x32_f16(bh[j], ah[i], acc[i][j], 0, 0, 0);
                acc[i][j] = __builtin_amdgcn_mfma_f32_16x16x32_f16(bl[j], ah[i], acc[i][j], 0, 0, 0);
                acc[i][j] = __builtin_amdgcn_mfma_f32_16x16x32_f16(bh[j], al[i], acc[i][j], 0, 0, 0);
            }
        __syncthreads();
    }

    const int rgrp = (lane >> 4) << 2;
    #pragma unroll
    for (int j = 0; j < 2; ++j) {
        const int obase = wc + (j << 4) + rgrp;      // o = reg-dim
        #pragma unroll
        for (int i = 0; i < 4; ++i) {
            const int jcol = m0 + wr + (i << 4) + l15; // j = lane&15 (coalesced)
            #pragma unroll
            for (int r = 0; r < 4; ++r)
                C[(size_t)(obase + r) * 512 + jcol] = acc[i][j][r];
        }
    }
}

// -------------------------------------------- geo MLP -> S[b,g,i,j] (base term)
__global__ __launch_bounds__(256) void geo_kernel(
    const float* __restrict__ gcx, const float* __restrict__ gcy,
    const float* __restrict__ gw,  const float* __restrict__ glw,
    const float* __restrict__ glh,
    const float* __restrict__ W_geo, const float* __restrict__ b_geo,
    const float* __restrict__ W_bgc, const float* __restrict__ b_bgc,
    float* __restrict__ S)
{
    __shared__ float sWg[256];
    __shared__ float sbg[64];
    __shared__ float sWb[1024];
    __shared__ float sbb[16];
    const int tid = threadIdx.x;
    const int bid = blockIdx.x;        // b*512 + i
    const int bb = bid >> 9;
    const int ii = bid & 511;

    sWg[tid] = W_geo[tid];
    if (tid < 64) sbg[tid] = b_geo[tid];
    if (tid < 16) sbb[tid] = b_bgc[tid];
    for (int l = tid; l < 1024; l += 256) sWb[l] = W_bgc[l];
    __syncthreads();

    const float cxi = gcx[bid], cyi = gcy[bid];
    const float rwi = 1.0f / gw[bid];
    const float lwi = glw[bid], lhi = glh[bid];

    for (int j = tid; j < 512; j += 256) {
        const int jg = (bb << 9) + j;
        const float e0 = __logf(fmaxf(fabsf((cxi - gcx[jg]) * rwi), 1e-3f));
        const float e1 = __logf(fmaxf(fabsf((cyi - gcy[jg]) * rwi), 1e-3f));
        const float e2 = lwi - glw[jg];
        const float e3 = lhi - glh[jg];
        float acc[16];
        #pragma unroll
        for (int g = 0; g < 16; ++g) acc[g] = 0.f;
        #pragma unroll 4
        for (int d = 0; d < 64; ++d) {
            float hv = fmaf(e0, sWg[d * 4 + 0], fmaf(e1, sWg[d * 4 + 1],
                       fmaf(e2, sWg[d * 4 + 2], fmaf(e3, sWg[d * 4 + 3], sbg[d]))));
            hv = fast_tanh(hv);
            #pragma unroll
            for (int g = 0; g < 16; ++g) acc[g] = fmaf(sWb[g * 64 + d], hv, acc[g]);
        }
        #pragma unroll
        for (int g = 0; g < 16; ++g) {
            const float v = fmaxf(acc[g] + sbb[g], 0.f);
            S[(((size_t)(bb * 16 + g) * 512 + ii) * 512) + j] = __logf(fmaxf(v, 1e-6f));
        }
    }
}

// --------------------------- S[b,g,i,j] += 0.125 * sum_d q[b,i,gd]*k[b,j,gd]
__global__ __launch_bounds__(256) void gemm_logits(
    const float* __restrict__ q, const float* __restrict__ k,
    float* __restrict__ S)
{
    const int z = blockIdx.z;
    const int b = z >> 4, g = z & 15;
    const int m0 = blockIdx.y << 6;     // i
    const int n0 = blockIdx.x << 6;     // j
    const float* A = q + ((size_t)b * 512 + m0) * 1024 + g * 64;
    const float* B = k + ((size_t)b * 512 + n0) * 1024 + g * 64;
    float* C = S + (size_t)z * 512 * 512;

    __shared__ float As[16][64];
    __shared__ float Bs[16][64];
    const int tid = threadIdx.x;
    const int tx = tid & 15, ty = tid >> 4;
    const int lr = tid >> 2;
    const int lk = (tid & 3) << 2;
    float acc[4][4] = {{0.f}};

    #pragma unroll
    for (int k0 = 0; k0 < 64; k0 += 16) {
        const float4 a4 = *reinterpret_cast<const float4*>(A + (size_t)lr * 1024 + k0 + lk);
        const float4 b4 = *reinterpret_cast<const float4*>(B + (size_t)lr * 1024 + k0 + lk);
        As[lk + 0][lr] = a4.x; As[lk + 1][lr] = a4.y;
        As[lk + 2][lr] = a4.z; As[lk + 3][lr] = a4.w;
        Bs[lk + 0][lr] = b4.x; Bs[lk + 1][lr] = b4.y;
        Bs[lk + 2][lr] = b4.z; Bs[lk + 3][lr] = b4.w;
        __syncthreads();
        #pragma unroll
        for (int kk = 0; kk < 16; ++kk) {
            float a[4], b[4];
            #pragma unroll
            for (int i = 0; i < 4; ++i) a[i] = As[kk][(ty << 2) + i];
            #pragma unroll
            for (int j = 0; j < 4; ++j) b[j] = Bs[kk][(tx << 2) + j];
            #pragma unroll
            for (int i = 0; i < 4; ++i)
                #pragma unroll
                for (int j = 0; j < 4; ++j) acc[i][j] = fmaf(a[i], b[j], acc[i][j]);
        }
        __syncthreads();
    }
    #pragma unroll
    for (int i = 0; i < 4; ++i) {
        const int row = m0 + (ty << 2) + i;
        #pragma unroll
        for (int j = 0; j < 4; ++j) {
            const int col = n0 + (tx << 2) + j;
            C[(size_t)row * 512 + col] += 0.125f * acc[i][j];
        }
    }
}

// ------------------------------------- softmax over j for each (b,g,i) row
__global__ __launch_bounds__(256) void softmax_kernel(float* __restrict__ S)
{
    const int lane = threadIdx.x & 63;
    const int wid = threadIdx.x >> 6;
    const size_t row = (size_t)blockIdx.x * 4 + wid;   // 65536 rows
    float* p = S + row * 512;
    float vals[8];
    float m = -3.0e38f;
    #pragma unroll
    for (int r = 0; r < 8; ++r) {
        vals[r] = p[(r << 6) + lane];
        m = fmaxf(m, vals[r]);
    }
    #pragma unroll
    for (int off = 32; off > 0; off >>= 1) m = fmaxf(m, __shfl_xor(m, off));
    float s = 0.f;
    #pragma unroll
    for (int r = 0; r < 8; ++r) { vals[r] = __expf(vals[r] - m); s += vals[r]; }
    #pragma unroll
    for (int off = 32; off > 0; off >>= 1) s += __shfl_xor(s, off);
    const float inv = 1.0f / s;
    #pragma unroll
    for (int r = 0; r < 8; ++r) p[(r << 6) + lane] = vals[r] * inv;
}

// --------- out[b,i,g*64+o] = relu(sum_j S[b,g,i,j]*y_t[b,g,o,j] + b_gc[g,o])
__global__ __launch_bounds__(256) void gemm_pv(
    const float* __restrict__ S, const float* __restrict__ y_t,
    const float* __restrict__ b_gc, float* __restrict__ out)
{
    const int z = blockIdx.z;
    const int b = z >> 4, g = z & 15;
    const int m0 = blockIdx.y << 6;
    const float* A = S + (size_t)z * 512 * 512 + (size_t)m0 * 512;  // rows i
    const float* B = y_t + (size_t)z * 64 * 512;                    // rows o

    __shared__ float As[16][64];
    __shared__ float Bs[16][64];
    const int tid = threadIdx.x;
    const int tx = tid & 15, ty = tid >> 4;
    const int lr = tid >> 2;
    const int lk = (tid & 3) << 2;
    float acc[4][4] = {{0.f}};

    for (int k0 = 0; k0 < 512; k0 += 16) {
        const float4 a4 = *reinterpret_cast<const float4*>(A + (size_t)lr * 512 + k0 + lk);
        const float4 b4 = *reinterpret_cast<const float4*>(B + (size_t)lr * 512 + k0 + lk);
        As[lk + 0][lr] = a4.x; As[lk + 1][lr] = a4.y;
        As[lk + 2][lr] = a4.z; As[lk + 3][lr] = a4.w;
        Bs[lk + 0][lr] = b4.x; Bs[lk + 1][lr] = b4.y;
        Bs[lk + 2][lr] = b4.z; Bs[lk + 3][lr] = b4.w;
        __syncthreads();
        #pragma unroll
        for (int kk = 0; kk < 16; ++kk) {
            float a[4], bv[4];
            #pragma unroll
            for (int i = 0; i < 4; ++i) a[i] = As[kk][(ty << 2) + i];
            #pragma unroll
            for (int j = 0; j < 4; ++j) bv[j] = Bs[kk][(tx << 2) + j];
            #pragma unroll
            for (int i = 0; i < 4; ++i)
                #pragma unroll
                for (int j = 0; j < 4; ++j) acc[i][j] = fmaf(a[i], bv[j], acc[i][j]);
        }
        __syncthreads();
    }
    #pragma unroll
    for (int i = 0; i < 4; ++i) {
        const int row = m0 + (ty << 2) + i;          // i
        #pragma unroll
        for (int j = 0; j < 4; ++j) {
            const int col = (tx << 2) + j;           // o
            const float v = fmaxf(acc[i][j] + b_gc[g * 64 + col], 0.f);
            out[((size_t)b * 512 + row) * 1024 + g * 64 + col] = v;
        }
    }
}

// ---------------------------------------------------------------- launch
extern "C" void kernel_launch(void* const* d_in, const int* in_sizes, int n_in,
                              void* d_out, int out_size, void* d_ws, size_t ws_size,
                              hipStream_t stream)
{
    (void)in_sizes; (void)n_in; (void)out_size; (void)ws_size;
    const float* x     = (const float*)d_in[0];
    const float* boxes = (const float*)d_in[1];
    const float* W_geo = (const float*)d_in[2];
    const float* b_geo = (const float*)d_in[3];
    const float* W_bgc = (const float*)d_in[4];
    const float* b_bgc = (const float*)d_in[5];
    const float* W_q   = (const float*)d_in[6];
    const float* b_q   = (const float*)d_in[7];
    const float* W_k   = (const float*)d_in[8];
    const float* b_k   = (const float*)d_in[9];
    const float* W_gc  = (const float*)d_in[10];
    const float* b_gc  = (const float*)d_in[11];
    float* out = (float*)d_out;

    float* fws = (float*)d_ws;
    float* gcx = fws;
    float* gcy = gcx + 4096;
    float* gw  = gcy + 4096;
    float* glw = gw  + 4096;
    float* glh = glw + 4096;
    float* qws = fws + 5 * 4096;              // [4096,1024] f32
    float* kws = qws + 4096 * 1024;           // [4096,1024] f32
    float* ytw = kws + 4096 * 1024;           // [8,16,64,512] f32
    float* Sws = ytw + 4096 * 1024;           // [8,16,512,512] f32 (134 MB)

    // f16 split scratch aliased into Sws head: consumed by the MFMA GEMMs,
    // then Sws is fully rewritten by geo_kernel later in the stream.
    f16* xs  = (f16*)Sws;                     // [4096,2048] f16 (16.8 MB)
    f16* wqs = xs  + (size_t)4096 * 2048;     // [1024,2048] f16
    f16* wks = wqs + (size_t)1024 * 2048;     // [1024,2048] f16
    f16* wgs = wks + (size_t)1024 * 2048;     // [1024,2048] f16 (W_gc as 1024x1024)

    geom_kernel<<<16, 256, 0, stream>>>(boxes, gcx, gcy, gw, glw, glh);
    split_f16_kernel<<<4096, 256, 0, stream>>>(x, xs);
    split_f16_kernel<<<1024, 256, 0, stream>>>(W_q, wqs);
    split_f16_kernel<<<1024, 256, 0, stream>>>(W_k, wks);
    split_f16_kernel<<<1024, 256, 0, stream>>>(W_gc, wgs);
    gemm_qk_f16<<<dim3(8, 32, 2), 256, 0, stream>>>(xs, wqs, wks, b_q, b_k, qws, kws);
    gemm_yt_f16<<<dim3(1, 4, 128), 256, 0, stream>>>(xs, wgs, ytw);
    geo_kernel<<<4096, 256, 0, stream>>>(gcx, gcy, gw, glw, glh,
                                         W_geo, b_geo, W_bgc, b_bgc, Sws);
    gemm_logits<<<dim3(8, 8, 128), 256, 0, stream>>>(qws, kws, Sws);
    softmax_kernel<<<16384, 256, 0, stream>>>(Sws);
    gemm_pv<<<dim3(1, 8, 128), 256, 0, stream>>>(Sws, ytw, b_gc, out);
}

// Round 2
// 383.379 us; speedup vs baseline: 2.1270x; 1.3604x over previous
//
#include <hip/hip_runtime.h>
#include <math.h>
#include <stdint.h>

// BS=8, ROI=512, D=1024, G=16, DH=64, GEO=64, N_total=4096
// All I/O float32.

using f16   = _Float16;
using f16x4 = __attribute__((ext_vector_type(4))) f16;
using f16x8 = __attribute__((ext_vector_type(8))) f16;
using f32x4 = __attribute__((ext_vector_type(4))) float;

__device__ __forceinline__ float fast_tanh(float x) {
    const float ax = fabsf(x);
    const float e = __expf(ax + ax);
    const float r = __builtin_amdgcn_rcpf(e + 1.0f);
    const float t = fmaf(-2.0f, r, 1.0f);
    return copysignf(t, x);
}

// async 16B/lane global->LDS copy; lds dest is wave-uniform, HW adds lane*16
__device__ __forceinline__ void cp16(void* lds, const void* g) {
    __builtin_amdgcn_global_load_lds(
        (const __attribute__((address_space(1))) uint32_t*)g,
        (__attribute__((address_space(3))) uint32_t*)lds, 16, 0, 0);
}

// ---------------------------------------------------------------- geometry
__global__ __launch_bounds__(256) void geom_kernel(
    const float* __restrict__ boxes,
    float* __restrict__ gcx, float* __restrict__ gcy,
    float* __restrict__ gw,  float* __restrict__ glw, float* __restrict__ glh)
{
    const int i = blockIdx.x * 256 + threadIdx.x;
    if (i >= 4096) return;
    const float x1 = boxes[i * 4 + 0];
    const float y1 = boxes[i * 4 + 1];
    const float x2 = boxes[i * 4 + 2];
    const float y2 = boxes[i * 4 + 3];
    const float w = x2 - x1, h = y2 - y1;
    gcx[i] = 0.5f * (x1 + x2);
    gcy[i] = 0.5f * (y1 + y2);
    gw[i]  = w;
    glw[i] = logf(w);
    glh[i] = logf(h);
}

// ------------------------------------------------- fp32 -> split f16 hi/lo pack
// dst row: 2048 f16; per 32-k chunk s: cols [64s,64s+64) = {hi 32 | lo 32},
// pre-swizzled by (row&7)<<3 (XOR on f16-index bits 3..5).
__global__ __launch_bounds__(256) void split_f16_kernel(
    const float* __restrict__ src, f16* __restrict__ dst)
{
    const int m = blockIdx.x;
    const int k = threadIdx.x << 2;
    const float4 v = *reinterpret_cast<const float4*>(src + (size_t)m * 1024 + k);
    f16x4 hi, lo;
    hi[0] = (f16)v.x; hi[1] = (f16)v.y; hi[2] = (f16)v.z; hi[3] = (f16)v.w;
    lo[0] = (f16)(v.x - (float)hi[0]);
    lo[1] = (f16)(v.y - (float)hi[1]);
    lo[2] = (f16)(v.z - (float)hi[2]);
    lo[3] = (f16)(v.w - (float)hi[3]);
    const int s  = k >> 5;
    const int ic = k & 31;
    const int sw = (m & 7) << 3;
    f16* base = dst + (size_t)m * 2048 + (s << 6);
    *reinterpret_cast<f16x4*>(base + (ic ^ sw))        = hi;
    *reinterpret_cast<f16x4*>(base + ((ic + 32) ^ sw)) = lo;
}

// ---------------------------------------- Q & K projections, split-f16 MFMA
// Writes q,k DIRECTLY in packed split-f16 layout (rows 2048 f16, swizzled).
__global__ __launch_bounds__(256) void gemm_qk_f16(
    const f16* __restrict__ xs, const f16* __restrict__ wqs, const f16* __restrict__ wks,
    const float* __restrict__ b_q, const float* __restrict__ b_k,
    f16* __restrict__ qp, f16* __restrict__ kp)
{
    const bool isK = (blockIdx.z != 0);
    const f16* Bmat   = isK ? wks : wqs;
    const float* bias = isK ? b_k : b_q;
    f16* Cp           = isK ? kp : qp;
    const int m0 = blockIdx.y << 7;
    const int n0 = blockIdx.x << 7;

    __shared__ f16 As[8192];   // [128 rows][64 f16], swizzled content
    __shared__ f16 Bs[8192];

    const int tid  = threadIdx.x;
    const int lane = tid & 63;
    const int w    = tid >> 6;
    const int wr   = (w >> 1) << 6;
    const int wc   = (w & 1) << 6;
    const int srow = lane >> 3;
    const int sseg = (lane & 7) << 4;
    const int l15  = lane & 15;
    const int kgrp = (lane >> 4) << 3;

    f32x4 acc[4][4] = {};

    int aoff[4], boff[4];
    #pragma unroll
    for (int f = 0; f < 4; ++f) {
        const int ra = wr + (f << 4) + l15;
        aoff[f] = (ra << 6) + (kgrp ^ ((ra & 7) << 3));
        const int rb = wc + (f << 4) + l15;
        boff[f] = (rb << 6) + (kgrp ^ ((rb & 7) << 3));
    }

    for (int s = 0; s < 32; ++s) {
        const size_t gb = (size_t)(s << 7) + sseg;
        #pragma unroll
        for (int it = 0; it < 4; ++it) {
            const int ch = (w << 2) + it;
            const int gr = (ch << 3) + srow;
            cp16((char*)As + (ch << 10), (const char*)xs   + (size_t)(m0 + gr) * 4096 + gb);
            cp16((char*)Bs + (ch << 10), (const char*)Bmat + (size_t)(n0 + gr) * 4096 + gb);
        }
        __syncthreads();

        f16x8 ah[4], al[4], bh[4], bl[4];
        #pragma unroll
        for (int f = 0; f < 4; ++f) {
            ah[f] = *reinterpret_cast<const f16x8*>(As + aoff[f]);
            al[f] = *reinterpret_cast<const f16x8*>(As + (aoff[f] ^ 32));
            bh[f] = *reinterpret_cast<const f16x8*>(Bs + boff[f]);
            bl[f] = *reinterpret_cast<const f16x8*>(Bs + (boff[f] ^ 32));
        }
        #pragma unroll
        for (int i = 0; i < 4; ++i)
            #pragma unroll
            for (int j = 0; j < 4; ++j) {
                acc[i][j] = __builtin_amdgcn_mfma_f32_16x16x32_f16(ah[i], bh[j], acc[i][j], 0, 0, 0);
                acc[i][j] = __builtin_amdgcn_mfma_f32_16x16x32_f16(al[i], bh[j], acc[i][j], 0, 0, 0);
                acc[i][j] = __builtin_amdgcn_mfma_f32_16x16x32_f16(ah[i], bl[j], acc[i][j], 0, 0, 0);
            }
        __syncthreads();
    }

    const int rgrp = (lane >> 4) << 2;
    #pragma unroll
    for (int j = 0; j < 4; ++j) {
        const int col = n0 + wc + (j << 4) + l15;
        const float bv = bias[col];
        const int s = col >> 5, ic = col & 31;
        #pragma unroll
        for (int i = 0; i < 4; ++i) {
            #pragma unroll
            for (int r = 0; r < 4; ++r) {
                const int row = m0 + wr + (i << 4) + rgrp + r;
                const float v = acc[i][j][r] + bv;
                const int sw = (row & 7) << 3;
                const f16 hv = (f16)v;
                const size_t base = ((size_t)row << 11) + (s << 6);
                Cp[base + (ic ^ sw)]        = hv;
                Cp[base + ((ic ^ sw) ^ 32)] = (f16)(v - (float)hv);
            }
        }
    }
}

// -------------------- y_t[b,g,o,j] = sum_d x[b,j,d]*W_gc[g,o,d], split-f16 MFMA
// Output: packed SINGLE f16 [z][o=64][512 f16], 64-j superchunks swizzled by (o&7)<<3.
__global__ __launch_bounds__(256) void gemm_yt_f16(
    const f16* __restrict__ xs, const f16* __restrict__ wgs,
    f16* __restrict__ Yt)
{
    const int z = blockIdx.z;            // b*16+g
    const int b = z >> 4, g = z & 15;
    const int m0 = blockIdx.y << 7;      // j tile base
    const f16* A    = xs  + (size_t)(b << 9) * 2048;
    const f16* Bmat = wgs + (size_t)(g << 6) * 2048;

    __shared__ f16 As[8192];   // [128][64]
    __shared__ f16 Bs[4096];   // [64][64]

    const int tid  = threadIdx.x;
    const int lane = tid & 63;
    const int w    = tid >> 6;
    const int wr   = (w >> 1) << 6;
    const int wc   = (w & 1) << 5;
    const int srow = lane >> 3;
    const int sseg = (lane & 7) << 4;
    const int l15  = lane & 15;
    const int kgrp = (lane >> 4) << 3;

    f32x4 acc[4][2] = {};

    int aoff[4], boff[2];
    #pragma unroll
    for (int f = 0; f < 4; ++f) {
        const int ra = wr + (f << 4) + l15;
        aoff[f] = (ra << 6) + (kgrp ^ ((ra & 7) << 3));
    }
    #pragma unroll
    for (int f = 0; f < 2; ++f) {
        const int rb = wc + (f << 4) + l15;
        boff[f] = (rb << 6) + (kgrp ^ ((rb & 7) << 3));
    }

    for (int s = 0; s < 32; ++s) {
        const size_t gb = (size_t)(s << 7) + sseg;
        #pragma unroll
        for (int it = 0; it < 4; ++it) {
            const int ch = (w << 2) + it;
            cp16((char*)As + (ch << 10),
                 (const char*)A + (size_t)(m0 + (ch << 3) + srow) * 4096 + gb);
        }
        #pragma unroll
        for (int it = 0; it < 2; ++it) {
            const int ch = (w << 1) + it;
            cp16((char*)Bs + (ch << 10),
                 (const char*)Bmat + (size_t)((ch << 3) + srow) * 4096 + gb);
        }
        __syncthreads();

        f16x8 ah[4], al[4], bh[2], bl[2];
        #pragma unroll
        for (int f = 0; f < 4; ++f) {
            ah[f] = *reinterpret_cast<const f16x8*>(As + aoff[f]);
            al[f] = *reinterpret_cast<const f16x8*>(As + (aoff[f] ^ 32));
        }
        #pragma unroll
        for (int f = 0; f < 2; ++f) {
            bh[f] = *reinterpret_cast<const f16x8*>(Bs + boff[f]);
            bl[f] = *reinterpret_cast<const f16x8*>(Bs + (boff[f] ^ 32));
        }
        #pragma unroll
        for (int i = 0; i < 4; ++i)
            #pragma unroll
            for (int j = 0; j < 2; ++j) {
                acc[i][j] = __builtin_amdgcn_mfma_f32_16x16x32_f16(bh[j], ah[i], acc[i][j], 0, 0, 0);
                acc[i][j] = __builtin_amdgcn_mfma_f32_16x16x32_f16(bl[j], ah[i], acc[i][j], 0, 0, 0);
                acc[i][j] = __builtin_amdgcn_mfma_f32_16x16x32_f16(bh[j], al[i], acc[i][j], 0, 0, 0);
            }
        __syncthreads();
    }

    const int rgrp = (lane >> 4) << 2;
    #pragma unroll
    for (int jj = 0; jj < 2; ++jj) {
        const int obase = wc + (jj << 4) + rgrp;
        #pragma unroll
        for (int i = 0; i < 4; ++i) {
            const int jcol = m0 + wr + (i << 4) + l15;
            const int jhi = (jcol >> 6) << 6, jlo = jcol & 63;
            #pragma unroll
            for (int r = 0; r < 4; ++r) {
                const int o = obase + r;
                Yt[((size_t)z << 15) + (o << 9) + jhi + (jlo ^ ((o & 7) << 3))]
                    = (f16)acc[i][jj][r];
            }
        }
    }
}

// ---------------- geo MLP via MFMA -> S_base[b,g,i,j] (f32)
// block = (i-tile of 8, b); 4 waves, wave handles 2 i's x 32 j-chunks of 16.
// Lane (h=lane>>4, p=lane&15) computes H[p, 8h+e] / H[p, 32+8h+e] directly in
// MFMA B-frag order (no LDS routing); 64->16 proj = 6 split-f16 MFMA.
__global__ __launch_bounds__(256) void geo_mfma(
    const float* __restrict__ gcx, const float* __restrict__ gcy,
    const float* __restrict__ gw,  const float* __restrict__ glw,
    const float* __restrict__ glh,
    const float* __restrict__ W_geo, const float* __restrict__ b_geo,
    const float* __restrict__ W_bgc, const float* __restrict__ b_bgc,
    float* __restrict__ S)
{
    __shared__ float4 sJ[512];
    __shared__ float  sI[8][5];

    const int tid  = threadIdx.x;
    const int lane = tid & 63;
    const int h    = lane >> 4;
    const int p    = lane & 15;
    const int w    = tid >> 6;
    const int it   = blockIdx.x;     // i-tile (8 i's)
    const int bb   = blockIdx.y;

    // per-lane W_geo table: d = 8h+e (kstep0) and 32+8h+e (kstep1)
    float4 wg0[8], wg1[8];
    float  bg0[8], bg1[8];
    #pragma unroll
    for (int e = 0; e < 8; ++e) {
        wg0[e] = *reinterpret_cast<const float4*>(W_geo + (((h << 3) + e) << 2));
        wg1[e] = *reinterpret_cast<const float4*>(W_geo + ((32 + (h << 3) + e) << 2));
        bg0[e] = b_geo[(h << 3) + e];
        bg1[e] = b_geo[32 + (h << 3) + e];
    }
    // W_bgc A-frags (row g = p, k = 8h+e), hi/lo split
    f16x8 wbh0, wbl0, wbh1, wbl1;
    #pragma unroll
    for (int e = 0; e < 8; ++e) {
        const float v0 = W_bgc[(p << 6) + (h << 3) + e];
        const f16 x0 = (f16)v0; wbh0[e] = x0; wbl0[e] = (f16)(v0 - (float)x0);
        const float v1 = W_bgc[(p << 6) + 32 + (h << 3) + e];
        const f16 x1 = (f16)v1; wbh1[e] = x1; wbl1[e] = (f16)(v1 - (float)x1);
    }
    float bb4[4];
    #pragma unroll
    for (int r = 0; r < 4; ++r) bb4[r] = b_bgc[(h << 2) + r];

    for (int j = tid; j < 512; j += 256) {
        const int jg = (bb << 9) + j;
        sJ[j] = make_float4(gcx[jg], gcy[jg], glw[jg], glh[jg]);
    }
    if (tid < 8) {
        const int ig = (bb << 9) + (it << 3) + tid;
        sI[tid][0] = gcx[ig]; sI[tid][1] = gcy[ig];
        sI[tid][2] = 1.0f / gw[ig];
        sI[tid][3] = glw[ig]; sI[tid][4] = glh[ig];
    }
    __syncthreads();

    for (int iw = 0; iw < 2; ++iw) {
        const int il = (w << 1) + iw;
        const float cxi = sI[il][0], cyi = sI[il][1];
        const float rwi = sI[il][2], lwi = sI[il][3], lhi = sI[il][4];
        const int irow = (it << 3) + il;

        for (int jc = 0; jc < 32; ++jc) {
            const float4 je = sJ[(jc << 4) + p];
            const float e0 = __logf(fmaxf(fabsf((cxi - je.x) * rwi), 1e-3f));
            const float e1 = __logf(fmaxf(fabsf((cyi - je.y) * rwi), 1e-3f));
            const float e2 = lwi - je.z;
            const float e3 = lhi - je.w;

            f16x8 hh0, hl0, hh1, hl1;
            #pragma unroll
            for (int e = 0; e < 8; ++e) {
                float t0 = fmaf(e0, wg0[e].x, fmaf(e1, wg0[e].y,
                           fmaf(e2, wg0[e].z, fmaf(e3, wg0[e].w, bg0[e]))));
                t0 = fast_tanh(t0);
                const f16 a0 = (f16)t0; hh0[e] = a0; hl0[e] = (f16)(t0 - (float)a0);
                float t1 = fmaf(e0, wg1[e].x, fmaf(e1, wg1[e].y,
                           fmaf(e2, wg1[e].z, fmaf(e3, wg1[e].w, bg1[e]))));
                t1 = fast_tanh(t1);
                const f16 a1 = (f16)t1; hh1[e] = a1; hl1[e] = (f16)(t1 - (float)a1);
            }
            f32x4 acc = {0.f, 0.f, 0.f, 0.f};
            acc = __builtin_amdgcn_mfma_f32_16x16x32_f16(wbh0, hh0, acc, 0, 0, 0);
            acc = __builtin_amdgcn_mfma_f32_16x16x32_f16(wbl0, hh0, acc, 0, 0, 0);
            acc = __builtin_amdgcn_mfma_f32_16x16x32_f16(wbh0, hl0, acc, 0, 0, 0);
            acc = __builtin_amdgcn_mfma_f32_16x16x32_f16(wbh1, hh1, acc, 0, 0, 0);
            acc = __builtin_amdgcn_mfma_f32_16x16x32_f16(wbl1, hh1, acc, 0, 0, 0);
            acc = __builtin_amdgcn_mfma_f32_16x16x32_f16(wbh1, hl1, acc, 0, 0, 0);

            #pragma unroll
            for (int r = 0; r < 4; ++r) {
                const float v = fmaxf(acc[r] + bb4[r], 0.f);
                const float sv = __logf(fmaxf(v, 1e-6f));
                S[((size_t)((bb << 4) + (h << 2) + r) << 18)
                  + ((size_t)irow << 9) + (jc << 4) + p] = sv;
            }
        }
    }
}

// ---------------- logits + softmax fused: per (z, i-tile 16):
// S_row = S_base + 0.125*q_g.k_g^T -> softmax over 512 j -> P packed f16,
// written IN-PLACE into the first half of the S rows (reads complete first).
__global__ __launch_bounds__(256) void logits_sm(
    const f16* __restrict__ qp, const f16* __restrict__ kp,
    float* __restrict__ S)
{
    __shared__ f16  Aq[16 * 128];     // 4 KB
    __shared__ f16  Bk[128 * 128];    // 32 KB
    __shared__ float Ss[16][514];     // ~33 KB

    const int tid  = threadIdx.x;
    const int lane = tid & 63;
    const int w    = tid >> 6;
    const int h    = lane >> 4;
    const int l15  = lane & 15;
    const int kgrp = h << 3;
    const int i0   = blockIdx.x << 4;
    const int z    = blockIdx.y;
    const int b    = z >> 4, g = z & 15;

    const char* qbytes = (const char*)qp + ((size_t)((b << 9) + i0)) * 4096 + (g << 8);
    const char* kbytes = (const char*)kp + ((size_t)(b << 9)) * 4096 + (g << 8);

    // stage q tile (16 rows x 256B)
    cp16((char*)Aq + (w << 10),
         qbytes + (size_t)((w << 2) + (lane >> 4)) * 4096 + ((lane & 15) << 4));

    for (int c = 0; c < 4; ++c) {
        const int j0 = c << 7;
        #pragma unroll
        for (int it = 0; it < 8; ++it) {
            const int row = (w << 2) + (it << 4) + (lane >> 4);
            cp16((char*)Bk + (w << 10) + (it << 12),
                 kbytes + (size_t)(j0 + row) * 4096 + ((lane & 15) << 4));
        }
        __syncthreads();

        f16x8 aqh[2], aql[2];
        #pragma unroll
        for (int s = 0; s < 2; ++s) {
            const int ai = (l15 << 7) + (s << 6) + (kgrp ^ ((l15 & 7) << 3));
            aqh[s] = *reinterpret_cast<const f16x8*>(Aq + ai);
            aql[s] = *reinterpret_cast<const f16x8*>(Aq + (ai ^ 32));
        }
        f32x4 acc[2] = {};
        #pragma unroll
        for (int f = 0; f < 2; ++f) {
            const int jr = (w << 5) + (f << 4) + l15;
            #pragma unroll
            for (int s = 0; s < 2; ++s) {
                const int bi = (jr << 7) + (s << 6) + (kgrp ^ ((jr & 7) << 3));
                const f16x8 bh = *reinterpret_cast<const f16x8*>(Bk + bi);
                const f16x8 bl = *reinterpret_cast<const f16x8*>(Bk + (bi ^ 32));
                acc[f] = __builtin_amdgcn_mfma_f32_16x16x32_f16(aqh[s], bh, acc[f], 0, 0, 0);
                acc[f] = __builtin_amdgcn_mfma_f32_16x16x32_f16(aql[s], bh, acc[f], 0, 0, 0);
                acc[f] = __builtin_amdgcn_mfma_f32_16x16x32_f16(aqh[s], bl, acc[f], 0, 0, 0);
            }
        }
        #pragma unroll
        for (int f = 0; f < 2; ++f) {
            const int jfull = j0 + (w << 5) + (f << 4) + l15;
            #pragma unroll
            for (int r = 0; r < 4; ++r) {
                const int irow = (h << 2) + r;
                const float sb = S[((size_t)((z << 9) + i0 + irow) << 9) + jfull];
                Ss[irow][jfull] = fmaf(0.125f, acc[f][r], sb);
            }
        }
        __syncthreads();
    }

    // softmax over 512 j + packed-f16 P write (in-place over S rows)
    #pragma unroll
    for (int rr = 0; rr < 4; ++rr) {
        const int row = (w << 2) + rr;
        float v[8];
        float m = -3.0e38f;
        #pragma unroll
        for (int t = 0; t < 8; ++t) {
            v[t] = Ss[row][(t << 6) + lane];
            m = fmaxf(m, v[t]);
        }
        #pragma unroll
        for (int off = 32; off > 0; off >>= 1) m = fmaxf(m, __shfl_xor(m, off));
        float ssum = 0.f;
        #pragma unroll
        for (int t = 0; t < 8; ++t) { v[t] = __expf(v[t] - m); ssum += v[t]; }
        #pragma unroll
        for (int off = 32; off > 0; off >>= 1) ssum += __shfl_xor(ssum, off);
        const float inv = 1.0f / ssum;
        f16* prow = (f16*)((char*)S + ((size_t)((z << 9) + i0 + row)) * 2048);
        const int sw = (row & 7) << 3;
        #pragma unroll
        for (int t = 0; t < 8; ++t)
            prow[(t << 6) + (lane ^ sw)] = (f16)(v[t] * inv);
    }
}

// ---------------- PV: out[b,i,g*64+o] = relu(sum_j P[i,j]*Yt[o,j] + b_gc[g,o])
// single-f16 MFMA; P rows read from S region (stride 2048 B), Yt packed f16.
__global__ __launch_bounds__(256) void pv_f16(
    const float* __restrict__ S, const f16* __restrict__ Yt,
    const float* __restrict__ b_gc, float* __restrict__ out)
{
    __shared__ f16 Ap[128 * 64];   // 16 KB
    __shared__ f16 By[64 * 64];    // 8 KB

    const int tid  = threadIdx.x;
    const int lane = tid & 63;
    const int w    = tid >> 6;
    const int h    = lane >> 4;
    const int l15  = lane & 15;
    const int kgrp = h << 3;
    const int i0   = blockIdx.x << 7;
    const int z    = blockIdx.y;
    const int b    = z >> 4, g = z & 15;
    const int wr   = (w >> 1) << 6;
    const int wc   = (w & 1) << 5;

    const char* pbytes = (const char*)S + ((size_t)((z << 9) + i0)) * 2048;
    const char* ybytes = (const char*)Yt + ((size_t)z << 16);

    f32x4 acc[4][2] = {};

    for (int t = 0; t < 8; ++t) {
        #pragma unroll
        for (int it = 0; it < 4; ++it) {
            const int row = (w << 3) + (it << 5) + (lane >> 3);
            cp16((char*)Ap + (w << 10) + (it << 12),
                 pbytes + (size_t)row * 2048 + (t << 7) + ((lane & 7) << 4));
        }
        #pragma unroll
        for (int it = 0; it < 2; ++it) {
            const int row = (w << 3) + (it << 5) + (lane >> 3);
            cp16((char*)By + (w << 10) + (it << 12),
                 ybytes + (size_t)row * 1024 + (t << 7) + ((lane & 7) << 4));
        }
        __syncthreads();

        f16x8 af[4][2], bf[2][2];
        #pragma unroll
        for (int f = 0; f < 4; ++f) {
            const int ra = wr + (f << 4) + l15;
            #pragma unroll
            for (int s = 0; s < 2; ++s) {
                const int off = (ra << 6) + (((s << 5) + kgrp) ^ ((ra & 7) << 3));
                af[f][s] = *reinterpret_cast<const f16x8*>(Ap + off);
            }
        }
        #pragma unroll
        for (int f2 = 0; f2 < 2; ++f2) {
            const int rb = wc + (f2 << 4) + l15;
            #pragma unroll
            for (int s = 0; s < 2; ++s) {
                const int off = (rb << 6) + (((s << 5) + kgrp) ^ ((rb & 7) << 3));
                bf[f2][s] = *reinterpret_cast<const f16x8*>(By + off);
            }
        }
        #pragma unroll
        for (int f = 0; f < 4; ++f)
            #pragma unroll
            for (int f2 = 0; f2 < 2; ++f2)
                #pragma unroll
                for (int s = 0; s < 2; ++s)
                    acc[f][f2] = __builtin_amdgcn_mfma_f32_16x16x32_f16(
                        af[f][s], bf[f2][s], acc[f][f2], 0, 0, 0);
        __syncthreads();
    }

    #pragma unroll
    for (int f2 = 0; f2 < 2; ++f2) {
        const int ocol = wc + (f2 << 4) + l15;
        const float bg = b_gc[(g << 6) + ocol];
        #pragma unroll
        for (int f = 0; f < 4; ++f) {
            #pragma unroll
            for (int r = 0; r < 4; ++r) {
                const int il = wr + (f << 4) + (h << 2) + r;
                out[((size_t)((b << 9) + i0 + il) << 10) + (g << 6) + ocol]
                    = fmaxf(acc[f][f2][r] + bg, 0.f);
            }
        }
    }
}

// ---------------------------------------------------------------- launch
extern "C" void kernel_launch(void* const* d_in, const int* in_sizes, int n_in,
                              void* d_out, int out_size, void* d_ws, size_t ws_size,
                              hipStream_t stream)
{
    (void)in_sizes; (void)n_in; (void)out_size; (void)ws_size;
    const float* x     = (const float*)d_in[0];
    const float* boxes = (const float*)d_in[1];
    const float* W_geo = (const float*)d_in[2];
    const float* b_geo = (const float*)d_in[3];
    const float* W_bgc = (const float*)d_in[4];
    const float* b_bgc = (const float*)d_in[5];
    const float* W_q   = (const float*)d_in[6];
    const float* b_q   = (const float*)d_in[7];
    const float* W_k   = (const float*)d_in[8];
    const float* b_k   = (const float*)d_in[9];
    const float* W_gc  = (const float*)d_in[10];
    const float* b_gc  = (const float*)d_in[11];
    float* out = (float*)d_out;

    float* fws = (float*)d_ws;
    float* gcx = fws;
    float* gcy = gcx + 4096;
    float* gw  = gcy + 4096;
    float* glw = gw  + 4096;
    float* glh = glw + 4096;
    f16* qp  = (f16*)(fws + 5 * 4096);            // [4096][2048] f16  16.8 MB
    f16* kp  = qp + (size_t)4096 * 2048;          // [4096][2048] f16  16.8 MB
    f16* ytp = kp + (size_t)4096 * 2048;          // [128][64][512] f16 8.4 MB
    float* Sws = (float*)(ytp + (size_t)128 * 64 * 512);  // [128][512][512] f32 134 MB

    // pack scratch aliased into Sws head (consumed before geo_mfma writes Sws)
    f16* xs  = (f16*)Sws;                         // [4096][2048] f16
    f16* wqs = xs  + (size_t)4096 * 2048;
    f16* wks = wqs + (size_t)1024 * 2048;
    f16* wgs = wks + (size_t)1024 * 2048;

    geom_kernel<<<16, 256, 0, stream>>>(boxes, gcx, gcy, gw, glw, glh);
    split_f16_kernel<<<4096, 256, 0, stream>>>(x, xs);
    split_f16_kernel<<<1024, 256, 0, stream>>>(W_q, wqs);
    split_f16_kernel<<<1024, 256, 0, stream>>>(W_k, wks);
    split_f16_kernel<<<1024, 256, 0, stream>>>(W_gc, wgs);
    gemm_qk_f16<<<dim3(8, 32, 2), 256, 0, stream>>>(xs, wqs, wks, b_q, b_k, qp, kp);
    gemm_yt_f16<<<dim3(1, 4, 128), 256, 0, stream>>>(xs, wgs, ytp);
    geo_mfma<<<dim3(64, 8), 256, 0, stream>>>(gcx, gcy, gw, glw, glh,
                                              W_geo, b_geo, W_bgc, b_bgc, Sws);
    logits_sm<<<dim3(32, 128), 256, 0, stream>>>(qp, kp, Sws);
    pv_f16<<<dim3(4, 128), 256, 0, stream>>>(Sws, ytp, b_gc, out);
}

// Round 5
// 320.251 us; speedup vs baseline: 2.5462x; 1.1971x over previous
//
#include <hip/hip_runtime.h>
#include <math.h>
#include <stdint.h>

// BS=8, ROI=512, D=1024, G=16, DH=64, GEO=64, N_total=4096
// All I/O float32.

using f16   = _Float16;
using f16x4 = __attribute__((ext_vector_type(4))) f16;
using f16x8 = __attribute__((ext_vector_type(8))) f16;
using f32x4 = __attribute__((ext_vector_type(4))) float;

__device__ __forceinline__ float fast_tanh(float x) {
    const float ax = fabsf(x);
    const float e = __expf(ax + ax);
    const float r = __builtin_amdgcn_rcpf(e + 1.0f);
    const float t = fmaf(-2.0f, r, 1.0f);
    return copysignf(t, x);
}

// async 16B/lane global->LDS copy; lds dest is wave-uniform, HW adds lane*16
__device__ __forceinline__ void cp16(void* lds, const void* g) {
    __builtin_amdgcn_global_load_lds(
        (const __attribute__((address_space(1))) uint32_t*)g,
        (__attribute__((address_space(3))) uint32_t*)lds, 16, 0, 0);
}

// ---------------------------------------------------------------- geometry
__global__ __launch_bounds__(256) void geom_kernel(
    const float* __restrict__ boxes,
    float* __restrict__ gcx, float* __restrict__ gcy,
    float* __restrict__ gw,  float* __restrict__ glw, float* __restrict__ glh)
{
    const int i = blockIdx.x * 256 + threadIdx.x;
    if (i >= 4096) return;
    const float x1 = boxes[i * 4 + 0];
    const float y1 = boxes[i * 4 + 1];
    const float x2 = boxes[i * 4 + 2];
    const float y2 = boxes[i * 4 + 3];
    const float w = x2 - x1, h = y2 - y1;
    gcx[i] = 0.5f * (x1 + x2);
    gcy[i] = 0.5f * (y1 + y2);
    gw[i]  = w;
    glw[i] = logf(w);
    glh[i] = logf(h);
}

// ------------------------------------------------- fp32 -> split f16 hi/lo pack
// dst row: 2048 f16; per 32-k chunk s: cols [64s,64s+64) = {hi 32 | lo 32},
// pre-swizzled by (row&7)<<3 (XOR on f16-index bits 3..5).
__global__ __launch_bounds__(256) void split_f16_kernel(
    const float* __restrict__ src, f16* __restrict__ dst)
{
    const int m = blockIdx.x;
    const int k = threadIdx.x << 2;
    const float4 v = *reinterpret_cast<const float4*>(src + (size_t)m * 1024 + k);
    f16x4 hi, lo;
    hi[0] = (f16)v.x; hi[1] = (f16)v.y; hi[2] = (f16)v.z; hi[3] = (f16)v.w;
    lo[0] = (f16)(v.x - (float)hi[0]);
    lo[1] = (f16)(v.y - (float)hi[1]);
    lo[2] = (f16)(v.z - (float)hi[2]);
    lo[3] = (f16)(v.w - (float)hi[3]);
    const int s  = k >> 5;
    const int ic = k & 31;
    const int sw = (m & 7) << 3;
    f16* base = dst + (size_t)m * 2048 + (s << 6);
    *reinterpret_cast<f16x4*>(base + (ic ^ sw))        = hi;
    *reinterpret_cast<f16x4*>(base + ((ic + 32) ^ sw)) = lo;
}

// ---------------------------------------- Q & K projections, split-f16 MFMA
// C[m,n] = sum_k A[m,k]*B[n,k] + bias[n]; coalesced f32 output.
__global__ __launch_bounds__(256) void gemm_qk_f16(
    const f16* __restrict__ xs, const f16* __restrict__ wqs, const f16* __restrict__ wks,
    const float* __restrict__ b_q, const float* __restrict__ b_k,
    float* __restrict__ qout, float* __restrict__ kout)
{
    const bool isK = (blockIdx.z != 0);
    const f16* Bmat   = isK ? wks : wqs;
    const float* bias = isK ? b_k : b_q;
    float* C          = isK ? kout : qout;
    const int m0 = blockIdx.y << 7;
    const int n0 = blockIdx.x << 7;

    __shared__ f16 As[8192];   // [128 rows][64 f16], swizzled content
    __shared__ f16 Bs[8192];

    const int tid  = threadIdx.x;
    const int lane = tid & 63;
    const int w    = tid >> 6;
    const int wr   = (w >> 1) << 6;
    const int wc   = (w & 1) << 6;
    const int srow = lane >> 3;
    const int sseg = (lane & 7) << 4;
    const int l15  = lane & 15;
    const int kgrp = (lane >> 4) << 3;

    f32x4 acc[4][4] = {};

    int aoff[4], boff[4];
    #pragma unroll
    for (int f = 0; f < 4; ++f) {
        const int ra = wr + (f << 4) + l15;
        aoff[f] = (ra << 6) + (kgrp ^ ((ra & 7) << 3));
        const int rb = wc + (f << 4) + l15;
        boff[f] = (rb << 6) + (kgrp ^ ((rb & 7) << 3));
    }

    for (int s = 0; s < 32; ++s) {
        const size_t gb = (size_t)(s << 7) + sseg;
        #pragma unroll
        for (int it = 0; it < 4; ++it) {
            const int ch = (w << 2) + it;
            const int gr = (ch << 3) + srow;
            cp16((char*)As + (ch << 10), (const char*)xs   + (size_t)(m0 + gr) * 4096 + gb);
            cp16((char*)Bs + (ch << 10), (const char*)Bmat + (size_t)(n0 + gr) * 4096 + gb);
        }
        __syncthreads();

        f16x8 ah[4], al[4], bh[4], bl[4];
        #pragma unroll
        for (int f = 0; f < 4; ++f) {
            ah[f] = *reinterpret_cast<const f16x8*>(As + aoff[f]);
            al[f] = *reinterpret_cast<const f16x8*>(As + (aoff[f] ^ 32));
            bh[f] = *reinterpret_cast<const f16x8*>(Bs + boff[f]);
            bl[f] = *reinterpret_cast<const f16x8*>(Bs + (boff[f] ^ 32));
        }
        #pragma unroll
        for (int i = 0; i < 4; ++i)
            #pragma unroll
            for (int j = 0; j < 4; ++j) {
                acc[i][j] = __builtin_amdgcn_mfma_f32_16x16x32_f16(ah[i], bh[j], acc[i][j], 0, 0, 0);
                acc[i][j] = __builtin_amdgcn_mfma_f32_16x16x32_f16(al[i], bh[j], acc[i][j], 0, 0, 0);
                acc[i][j] = __builtin_amdgcn_mfma_f32_16x16x32_f16(ah[i], bl[j], acc[i][j], 0, 0, 0);
            }
        __syncthreads();
    }

    const int rgrp = (lane >> 4) << 2;
    #pragma unroll
    for (int j = 0; j < 4; ++j) {
        const int col = n0 + wc + (j << 4) + l15;
        const float bv = bias[col];
        #pragma unroll
        for (int i = 0; i < 4; ++i) {
            const int row = m0 + wr + (i << 4) + rgrp;
            #pragma unroll
            for (int r = 0; r < 4; ++r)
                C[(size_t)(row + r) * 1024 + col] = acc[i][j][r] + bv;
        }
    }
}

// -------------------- y_t[b,g,o,j] = sum_d x[b,j,d]*W_gc[g,o,d], split-f16 MFMA
// Output: packed SINGLE f16 [z][o=64][512 f16], 64-j superchunks swizzled by (o&7)<<3.
__global__ __launch_bounds__(256) void gemm_yt_f16(
    const f16* __restrict__ xs, const f16* __restrict__ wgs,
    f16* __restrict__ Yt)
{
    const int z = blockIdx.z;            // b*16+g
    const int b = z >> 4, g = z & 15;
    const int m0 = blockIdx.y << 7;      // j tile base
    const f16* A    = xs  + (size_t)(b << 9) * 2048;
    const f16* Bmat = wgs + (size_t)(g << 6) * 2048;

    __shared__ f16 As[8192];   // [128][64]
    __shared__ f16 Bs[4096];   // [64][64]

    const int tid  = threadIdx.x;
    const int lane = tid & 63;
    const int w    = tid >> 6;
    const int wr   = (w >> 1) << 6;
    const int wc   = (w & 1) << 5;
    const int srow = lane >> 3;
    const int sseg = (lane & 7) << 4;
    const int l15  = lane & 15;
    const int kgrp = (lane >> 4) << 3;

    f32x4 acc[4][2] = {};

    int aoff[4], boff[2];
    #pragma unroll
    for (int f = 0; f < 4; ++f) {
        const int ra = wr + (f << 4) + l15;
        aoff[f] = (ra << 6) + (kgrp ^ ((ra & 7) << 3));
    }
    #pragma unroll
    for (int f = 0; f < 2; ++f) {
        const int rb = wc + (f << 4) + l15;
        boff[f] = (rb << 6) + (kgrp ^ ((rb & 7) << 3));
    }

    for (int s = 0; s < 32; ++s) {
        const size_t gb = (size_t)(s << 7) + sseg;
        #pragma unroll
        for (int it = 0; it < 4; ++it) {
            const int ch = (w << 2) + it;
            cp16((char*)As + (ch << 10),
                 (const char*)A + (size_t)(m0 + (ch << 3) + srow) * 4096 + gb);
        }
        #pragma unroll
        for (int it = 0; it < 2; ++it) {
            const int ch = (w << 1) + it;
            cp16((char*)Bs + (ch << 10),
                 (const char*)Bmat + (size_t)((ch << 3) + srow) * 4096 + gb);
        }
        __syncthreads();

        f16x8 ah[4], al[4], bh[2], bl[2];
        #pragma unroll
        for (int f = 0; f < 4; ++f) {
            ah[f] = *reinterpret_cast<const f16x8*>(As + aoff[f]);
            al[f] = *reinterpret_cast<const f16x8*>(As + (aoff[f] ^ 32));
        }
        #pragma unroll
        for (int f = 0; f < 2; ++f) {
            bh[f] = *reinterpret_cast<const f16x8*>(Bs + boff[f]);
            bl[f] = *reinterpret_cast<const f16x8*>(Bs + (boff[f] ^ 32));
        }
        #pragma unroll
        for (int i = 0; i < 4; ++i)
            #pragma unroll
            for (int j = 0; j < 2; ++j) {
                acc[i][j] = __builtin_amdgcn_mfma_f32_16x16x32_f16(bh[j], ah[i], acc[i][j], 0, 0, 0);
                acc[i][j] = __builtin_amdgcn_mfma_f32_16x16x32_f16(bl[j], ah[i], acc[i][j], 0, 0, 0);
                acc[i][j] = __builtin_amdgcn_mfma_f32_16x16x32_f16(bh[j], al[i], acc[i][j], 0, 0, 0);
            }
        __syncthreads();
    }

    const int rgrp = (lane >> 4) << 2;
    #pragma unroll
    for (int jj = 0; jj < 2; ++jj) {
        const int obase = wc + (jj << 4) + rgrp;
        #pragma unroll
        for (int i = 0; i < 4; ++i) {
            const int jcol = m0 + wr + (i << 4) + l15;
            const int jhi = (jcol >> 6) << 6, jlo = jcol & 63;
            #pragma unroll
            for (int r = 0; r < 4; ++r) {
                const int o = obase + r;
                Yt[((size_t)z << 15) + (o << 9) + jhi + (jlo ^ ((o & 7) << 3))]
                    = (f16)acc[i][jj][r];
            }
        }
    }
}

// ---------------- geo MLP via MFMA -> S[z][i][j] = clamped softmax WEIGHT (f16)
// grid (256, 8): block = 2 i rows; 4 waves split j (8 chunks of 16 each).
// SPLIT hi/lo f16 on both W_bgc and H (3-term, 6 MFMA) — single-f16 here gave
// ~1e-3 abs error on w, which is unbounded RELATIVE error near relu()=0 and
// blew up the w-domain softmax (R3 failure, absmax 0.84).
__global__ __launch_bounds__(256) void geo_mfma(
    const float* __restrict__ gcx, const float* __restrict__ gcy,
    const float* __restrict__ gw,  const float* __restrict__ glw,
    const float* __restrict__ glh,
    const float* __restrict__ W_geo, const float* __restrict__ b_geo,
    const float* __restrict__ W_bgc, const float* __restrict__ b_bgc,
    f16* __restrict__ S)
{
    __shared__ float4 sJ[512];
    __shared__ float  sI[2][5];

    const int tid  = threadIdx.x;
    const int lane = tid & 63;
    const int h    = lane >> 4;
    const int p    = lane & 15;
    const int w    = tid >> 6;
    const int it   = blockIdx.x;     // i-pair index (2 i's per block)
    const int bb   = blockIdx.y;

    float4 wg0[8], wg1[8];
    float  bg0[8], bg1[8];
    #pragma unroll
    for (int e = 0; e < 8; ++e) {
        wg0[e] = *reinterpret_cast<const float4*>(W_geo + (((h << 3) + e) << 2));
        wg1[e] = *reinterpret_cast<const float4*>(W_geo + ((32 + (h << 3) + e) << 2));
        bg0[e] = b_geo[(h << 3) + e];
        bg1[e] = b_geo[32 + (h << 3) + e];
    }
    f16x8 wbh0, wbl0, wbh1, wbl1;
    #pragma unroll
    for (int e = 0; e < 8; ++e) {
        const float v0 = W_bgc[(p << 6) + (h << 3) + e];
        const f16 x0 = (f16)v0; wbh0[e] = x0; wbl0[e] = (f16)(v0 - (float)x0);
        const float v1 = W_bgc[(p << 6) + 32 + (h << 3) + e];
        const f16 x1 = (f16)v1; wbh1[e] = x1; wbl1[e] = (f16)(v1 - (float)x1);
    }
    float bb4[4];
    #pragma unroll
    for (int r = 0; r < 4; ++r) bb4[r] = b_bgc[(h << 2) + r];

    for (int l = tid; l < 512; l += 256) {
        const int jg = (bb << 9) + l;
        sJ[l] = make_float4(gcx[jg], gcy[jg], glw[jg], glh[jg]);
    }
    if (tid < 2) {
        const int ig = (bb << 9) + (it << 1) + tid;
        sI[tid][0] = gcx[ig]; sI[tid][1] = gcy[ig];
        sI[tid][2] = 1.0f / gw[ig];
        sI[tid][3] = glw[ig]; sI[tid][4] = glh[ig];
    }
    __syncthreads();

    for (int il = 0; il < 2; ++il) {
        const float cxi = sI[il][0], cyi = sI[il][1];
        const float rwi = sI[il][2], lwi = sI[il][3], lhi = sI[il][4];
        const int irow = (it << 1) + il;

        for (int c = 0; c < 8; ++c) {
            const int jc = (w << 3) + c;
            const float4 je = sJ[(jc << 4) + p];
            const float e0 = __logf(fmaxf(fabsf((cxi - je.x) * rwi), 1e-3f));
            const float e1 = __logf(fmaxf(fabsf((cyi - je.y) * rwi), 1e-3f));
            const float e2 = lwi - je.z;
            const float e3 = lhi - je.w;

            f16x8 hh0, hl0, hh1, hl1;
            #pragma unroll
            for (int e = 0; e < 8; ++e) {
                float t0 = fmaf(e0, wg0[e].x, fmaf(e1, wg0[e].y,
                           fmaf(e2, wg0[e].z, fmaf(e3, wg0[e].w, bg0[e]))));
                t0 = fast_tanh(t0);
                const f16 a0 = (f16)t0; hh0[e] = a0; hl0[e] = (f16)(t0 - (float)a0);
                float t1 = fmaf(e0, wg1[e].x, fmaf(e1, wg1[e].y,
                           fmaf(e2, wg1[e].z, fmaf(e3, wg1[e].w, bg1[e]))));
                t1 = fast_tanh(t1);
                const f16 a1 = (f16)t1; hh1[e] = a1; hl1[e] = (f16)(t1 - (float)a1);
            }
            f32x4 acc = {0.f, 0.f, 0.f, 0.f};
            acc = __builtin_amdgcn_mfma_f32_16x16x32_f16(wbh0, hh0, acc, 0, 0, 0);
            acc = __builtin_amdgcn_mfma_f32_16x16x32_f16(wbl0, hh0, acc, 0, 0, 0);
            acc = __builtin_amdgcn_mfma_f32_16x16x32_f16(wbh0, hl0, acc, 0, 0, 0);
            acc = __builtin_amdgcn_mfma_f32_16x16x32_f16(wbh1, hh1, acc, 0, 0, 0);
            acc = __builtin_amdgcn_mfma_f32_16x16x32_f16(wbl1, hh1, acc, 0, 0, 0);
            acc = __builtin_amdgcn_mfma_f32_16x16x32_f16(wbh1, hl1, acc, 0, 0, 0);

            f16* sp = S + ((size_t)((bb << 4) + (h << 2)) << 18)
                        + ((size_t)irow << 9) + (jc << 4) + p;
            #pragma unroll
            for (int r = 0; r < 4; ++r)
                sp[(size_t)r << 18] = (f16)fmaxf(fmaxf(acc[r] + bb4[r], 0.f), 1e-6f);
        }
    }
}

// ---------------- fused logits + softmax + PV. Per block: (z, 16 i-rows).
// B-fragments (k, Yt) read per-lane DIRECTLY from packed global (L2-resident
// per z); only Ss + P in LDS -> 2 barriers total.
// p_j = w_j * exp(l_j - m) / sum  (identical to softmax(log w + l)).
__global__ __launch_bounds__(256) void attn_fused(
    const f16* __restrict__ qp, const f16* __restrict__ kp,
    const f16* __restrict__ Sb, const f16* __restrict__ Yt,
    const float* __restrict__ b_gc, float* __restrict__ out)
{
    __shared__ float Ss[16][514];   // ~33 KB
    __shared__ f16   P[16 * 512];   // 16 KB

    const int tid  = threadIdx.x;
    const int lane = tid & 63;
    const int w    = tid >> 6;
    const int h    = lane >> 4;
    const int p_   = lane & 15;
    const int kgrp = h << 3;
    const int i0   = blockIdx.x << 4;
    const int z    = blockIdx.y;
    const int b    = z >> 4, g = z & 15;

    const char* qbytes = (const char*)qp + ((size_t)((b << 9) + i0)) * 4096 + (g << 8);
    const char* kbytes = (const char*)kp + ((size_t)(b << 9)) * 4096 + (g << 8);

    // q A-frags direct from global (A row = i = p_)
    f16x8 aqh[2], aql[2];
    {
        const char* qrow = qbytes + (size_t)p_ * 4096;
        #pragma unroll
        for (int s = 0; s < 2; ++s) {
            const int bo = (s << 6) + (kgrp ^ ((p_ & 7) << 3));
            aqh[s] = *reinterpret_cast<const f16x8*>(qrow + bo * 2);
            aql[s] = *reinterpret_cast<const f16x8*>(qrow + (bo ^ 32) * 2);
        }
    }

    // ---- logits: each wave owns j in [w*128, w*128+128)
    #pragma unroll
    for (int f = 0; f < 8; ++f) {
        const int j = (w << 7) + (f << 4) + p_;
        const char* krow = kbytes + (size_t)j * 4096;
        f32x4 a = {0.f, 0.f, 0.f, 0.f};
        #pragma unroll
        for (int s = 0; s < 2; ++s) {
            const int bo = (s << 6) + (kgrp ^ ((j & 7) << 3));
            const f16x8 bh = *reinterpret_cast<const f16x8*>(krow + bo * 2);
            const f16x8 bl = *reinterpret_cast<const f16x8*>(krow + (bo ^ 32) * 2);
            a = __builtin_amdgcn_mfma_f32_16x16x32_f16(aqh[s], bh, a, 0, 0, 0);
            a = __builtin_amdgcn_mfma_f32_16x16x32_f16(aql[s], bh, a, 0, 0, 0);
            a = __builtin_amdgcn_mfma_f32_16x16x32_f16(aqh[s], bl, a, 0, 0, 0);
        }
        #pragma unroll
        for (int r = 0; r < 4; ++r)
            Ss[(h << 2) + r][(w << 7) + (f << 4) + p_] = 0.125f * a[r];
    }
    __syncthreads();

    // ---- softmax with geo-weight multiply (4 rows per wave)
    #pragma unroll
    for (int rr = 0; rr < 4; ++rr) {
        const int row = (w << 2) + rr;
        const f16* wbp = Sb + ((size_t)z << 18) + ((size_t)(i0 + row) << 9);
        float l[8];
        float m = -3.0e38f;
        #pragma unroll
        for (int t = 0; t < 8; ++t) { l[t] = Ss[row][(t << 6) + lane]; m = fmaxf(m, l[t]); }
        #pragma unroll
        for (int off = 32; off > 0; off >>= 1) m = fmaxf(m, __shfl_xor(m, off));
        float wb[8];
        #pragma unroll
        for (int t = 0; t < 8; ++t) wb[t] = (float)wbp[(t << 6) + lane];
        float ssum = 0.f;
        #pragma unroll
        for (int t = 0; t < 8; ++t) { l[t] = wb[t] * __expf(l[t] - m); ssum += l[t]; }
        #pragma unroll
        for (int off = 32; off > 0; off >>= 1) ssum += __shfl_xor(ssum, off);
        const float inv = 1.0f / ssum;
        const int sw = (row & 7) << 3;
        f16* prow = P + (row << 9);
        #pragma unroll
        for (int t = 0; t < 8; ++t)
            prow[(t << 6) + (lane ^ sw)] = (f16)(l[t] * inv);
    }
    __syncthreads();

    // ---- PV: out 16i x 64o; wave w owns o-frag [w*16, w*16+16)
    const int o = (w << 4) + p_;
    const f16* ytz = Yt + ((size_t)z << 15) + ((size_t)o << 9);
    const f16* pr  = P + (p_ << 9);
    f32x4 av = {0.f, 0.f, 0.f, 0.f};
    #pragma unroll
    for (int t = 0; t < 8; ++t) {
        #pragma unroll
        for (int s = 0; s < 2; ++s) {
            const int ko = (s << 5) + kgrp;
            const f16x8 bf = *reinterpret_cast<const f16x8*>(ytz + (t << 6) + (ko ^ ((o  & 7) << 3)));
            const f16x8 af = *reinterpret_cast<const f16x8*>(pr  + (t << 6) + (ko ^ ((p_ & 7) << 3)));
            av = __builtin_amdgcn_mfma_f32_16x16x32_f16(af, bf, av, 0, 0, 0);
        }
    }
    const float bg = b_gc[(g << 6) + o];
    float* orow = out + ((size_t)((b << 9) + i0)) * 1024 + (g << 6) + o;
    #pragma unroll
    for (int r = 0; r < 4; ++r)
        orow[(size_t)((h << 2) + r) * 1024] = fmaxf(av[r] + bg, 0.f);
}

// ---------------------------------------------------------------- launch
extern "C" void kernel_launch(void* const* d_in, const int* in_sizes, int n_in,
                              void* d_out, int out_size, void* d_ws, size_t ws_size,
                              hipStream_t stream)
{
    (void)in_sizes; (void)n_in; (void)out_size; (void)ws_size;
    const float* x     = (const float*)d_in[0];
    const float* boxes = (const float*)d_in[1];
    const float* W_geo = (const float*)d_in[2];
    const float* b_geo = (const float*)d_in[3];
    const float* W_bgc = (const float*)d_in[4];
    const float* b_bgc = (const float*)d_in[5];
    const float* W_q   = (const float*)d_in[6];
    const float* b_q   = (const float*)d_in[7];
    const float* W_k   = (const float*)d_in[8];
    const float* b_k   = (const float*)d_in[9];
    const float* W_gc  = (const float*)d_in[10];
    const float* b_gc  = (const float*)d_in[11];
    float* out = (float*)d_out;

    float* fws = (float*)d_ws;
    float* gcx = fws;
    float* gcy = gcx + 4096;
    float* gw  = gcy + 4096;
    float* glw = gw  + 4096;
    float* glh = glw + 4096;
    f16* qp  = (f16*)(fws + 5 * 4096);            // [4096][2048] f16  16.8 MB
    f16* kp  = qp + (size_t)4096 * 2048;          // [4096][2048] f16  16.8 MB
    f16* ytp = kp + (size_t)4096 * 2048;          // [128][64][512] f16 8.4 MB
    f16* Sws = ytp + (size_t)128 * 64 * 512;      // [128][512][512] f16 67.1 MB

    // scratch aliased into Sws head (all consumed before geo_mfma writes Sws)
    f16* xs  = Sws;                               // [4096][2048] f16 16.8 MB
    f16* wqs = xs  + (size_t)4096 * 2048;
    f16* wks = wqs + (size_t)1024 * 2048;
    f16* wgs = wks + (size_t)1024 * 2048;
    float* qws = (float*)(wgs + (size_t)1024 * 2048);  // [4096][1024] f32
    float* kws = qws + (size_t)4096 * 1024;            // [4096][1024] f32

    geom_kernel<<<16, 256, 0, stream>>>(boxes, gcx, gcy, gw, glw, glh);
    split_f16_kernel<<<4096, 256, 0, stream>>>(x, xs);
    split_f16_kernel<<<1024, 256, 0, stream>>>(W_q, wqs);
    split_f16_kernel<<<1024, 256, 0, stream>>>(W_k, wks);
    split_f16_kernel<<<1024, 256, 0, stream>>>(W_gc, wgs);
    gemm_qk_f16<<<dim3(8, 32, 2), 256, 0, stream>>>(xs, wqs, wks, b_q, b_k, qws, kws);
    split_f16_kernel<<<4096, 256, 0, stream>>>(qws, qp);
    split_f16_kernel<<<4096, 256, 0, stream>>>(kws, kp);
    gemm_yt_f16<<<dim3(1, 4, 128), 256, 0, stream>>>(xs, wgs, ytp);
    geo_mfma<<<dim3(256, 8), 256, 0, stream>>>(gcx, gcy, gw, glw, glh,
                                               W_geo, b_geo, W_bgc, b_bgc, Sws);
    attn_fused<<<dim3(32, 128), 256, 0, stream>>>(qp, kp, Sws, ytp, b_gc, out);
}